// Round 7
// baseline (87.254 us; speedup 1.0000x reference)
//
#include <hip/hip_runtime.h>
#include <hip/hip_bf16.h>

#define BATCH 4
#define SEQ   4096
#define EMB   1024
#define HS    64

typedef __attribute__((ext_vector_type(4)))  short  short4v;
typedef __attribute__((ext_vector_type(8)))  short  short8v;
typedef __attribute__((ext_vector_type(4)))  float  float4v;
typedef __attribute__((ext_vector_type(16))) float  float16v;
typedef __attribute__((ext_vector_type(8)))  unsigned short ushort8v;

// Q pre-scale: 1/sqrt(64) * log2(e) so softmax can use exp2 directly.
#define QSCALE 0.1803368801111204f

static __device__ __forceinline__ unsigned short f2bf(float f){
  __hip_bfloat16 h = __float2bfloat16(f);
  return *reinterpret_cast<unsigned short*>(&h);
}

// pack 2 floats -> 2 bf16 in one dword (round-half-up; inputs are finite, >=0 here ok)
static __device__ __forceinline__ int pk2(float va, float vb){
  unsigned ua = __float_as_uint(va), ub = __float_as_uint(vb);
  return (int)(((ua + 0x8000u) >> 16) | ((ub + 0x8000u) & 0xFFFF0000u));
}

// 32x32x16 bf16 (gfx950 full-rate). C/D (HW-verified m74/m101):
//   n = lane&31 (col), m = (reg&3) + 8*(reg>>2) + 4*(lane>>5) (row).
// A: row m=lane&31, k = 8*(lane>>5)+j ; B: col n=lane&31, k = 8*(lane>>5)+j.
// (k-placement used consistently on A and B -> any true HW k-permutation cancels;
//  validated end-to-end by proj_mfma passing in round 6.)
static __device__ __forceinline__ float16v mfma32(short8v a, short8v b, float16v c){
#if __has_builtin(__builtin_amdgcn_mfma_f32_32x32x16_bf16)
  return __builtin_amdgcn_mfma_f32_32x32x16_bf16(a, b, c, 0, 0, 0);
#else
  asm("v_mfma_f32_32x32x16_bf16 %0, %1, %2, %0" : "+v"(c) : "v"(a), "v"(b));
  return c;
#endif
}

// ---------------- W pack for 32x32 frags ----------------
// Wpack32[kstep 0..63][tile 0..5][lane 0..63][j 0..7] bf16 (384 KB total)
//   holds B[k][n]: k = kstep*16 + (lane>>5)*8 + j, n = tile*32 + (lane&31)
//   tiles 0,1 -> Q (scaled by QSCALE), 2,3 -> K, 4,5 -> V
__global__ __launch_bounds__(256) void pack32_kernel(
    const float* __restrict__ Wq, const float* __restrict__ Wk, const float* __restrict__ Wv,
    unsigned short* __restrict__ Wpack){
  const int flat = blockIdx.x * 256 + threadIdx.x;   // 0..24575
  const int lane = flat & 63;
  const int f    = flat >> 6;                        // kstep*6 + tile
  const int tile = f % 6;
  const int kstep= f / 6;
  const int k0   = kstep * 16 + (lane >> 5) * 8;
  const int mat  = tile >> 1;
  const int col  = (tile & 1) * 32 + (lane & 31);
  const float* W = (mat == 0) ? Wq : (mat == 1) ? Wk : Wv;
  const float scale = (mat == 0) ? QSCALE : 1.0f;
  short8v pk;
  #pragma unroll
  for (int j = 0; j < 8; ++j) pk[j] = (short)f2bf(W[(size_t)(k0 + j) * HS + col] * scale);
  *reinterpret_cast<short8v*>(Wpack + (size_t)flat * 8) = pk;
}

// ---------------- projection GEMM: K-split, 32x32 MFMA (unchanged, round 6) ----------------
#define LP 198
__global__ __launch_bounds__(512, 4) void proj_mfma(
    const float* __restrict__ x, const unsigned short* __restrict__ Wpack,
    unsigned short* __restrict__ Qb, unsigned short* __restrict__ Kb,
    unsigned short* __restrict__ Vt){
  __shared__ float Red[32 * LP];
  const int tid  = threadIdx.x;
  const int lane = tid & 63;
  const int w    = tid >> 6;
  const int kq   = w >> 1;
  const int cg   = w & 1;
  const int grow0 = blockIdx.x * 32;

  float16v acc0 = {0,0,0,0,0,0,0,0,0,0,0,0,0,0,0,0};
  float16v acc1 = {0,0,0,0,0,0,0,0,0,0,0,0,0,0,0,0};
  float16v acc2 = {0,0,0,0,0,0,0,0,0,0,0,0,0,0,0,0};

  const float* xr = x + (size_t)(grow0 + (lane & 31)) * EMB + kq * 256 + ((lane >> 5) << 3);
  const unsigned short* wp = Wpack + lane * 8;
  const int fbase = (kq * 16) * 6 + cg * 3;

  float4 xa0 = *reinterpret_cast<const float4*>(xr);
  float4 xa1 = *reinterpret_cast<const float4*>(xr + 4);
  short8v b0 = *reinterpret_cast<const short8v*>(wp + (size_t)(fbase    ) * 512);
  short8v b1 = *reinterpret_cast<const short8v*>(wp + (size_t)(fbase + 1) * 512);
  short8v b2 = *reinterpret_cast<const short8v*>(wp + (size_t)(fbase + 2) * 512);

  #pragma unroll
  for (int t = 0; t < 16; ++t){
    short8v af;
    af[0] = (short)f2bf(xa0.x); af[1] = (short)f2bf(xa0.y);
    af[2] = (short)f2bf(xa0.z); af[3] = (short)f2bf(xa0.w);
    af[4] = (short)f2bf(xa1.x); af[5] = (short)f2bf(xa1.y);
    af[6] = (short)f2bf(xa1.z); af[7] = (short)f2bf(xa1.w);
    float4 nx0, nx1; short8v nb0, nb1, nb2;
    if (t < 15){
      nx0 = *reinterpret_cast<const float4*>(xr + (t + 1) * 16);
      nx1 = *reinterpret_cast<const float4*>(xr + (t + 1) * 16 + 4);
      const unsigned short* wk = wp + (size_t)(fbase + (t + 1) * 6) * 512;
      nb0 = *reinterpret_cast<const short8v*>(wk);
      nb1 = *reinterpret_cast<const short8v*>(wk + 512);
      nb2 = *reinterpret_cast<const short8v*>(wk + 1024);
    }
    acc0 = mfma32(af, b0, acc0);
    acc1 = mfma32(af, b1, acc1);
    acc2 = mfma32(af, b2, acc2);
    if (t < 15){ xa0 = nx0; xa1 = nx1; b0 = nb0; b1 = nb1; b2 = nb2; }
  }

  const int colb = cg * 96 + (lane & 31);
  const int rsh  = 4 * (lane >> 5);
  #define RED_OP(op) { \
    _Pragma("unroll") \
    for (int reg = 0; reg < 16; ++reg){ \
      const int row = (reg & 3) + 8 * (reg >> 2) + rsh; \
      Red[row * LP + colb     ] op acc0[reg]; \
      Red[row * LP + colb + 32] op acc1[reg]; \
      Red[row * LP + colb + 64] op acc2[reg]; \
    }}
  if (kq == 0) RED_OP(=)
  __syncthreads();
  if (kq == 1) RED_OP(+=)
  __syncthreads();
  if (kq == 2) RED_OP(+=)
  __syncthreads();
  if (kq == 3) RED_OP(+=)
  __syncthreads();
  #undef RED_OP

  {
    const int row = tid >> 4;
    const int c16 = tid & 15;
    ushort8v pk;
    #pragma unroll
    for (int i = 0; i < 8; ++i) pk[i] = f2bf(Red[row * LP + c16 * 8 + i]);
    unsigned short* dst = (c16 < 8) ? (Qb + (size_t)(grow0 + row) * HS + c16 * 8)
                                    : (Kb + (size_t)(grow0 + row) * HS + (c16 - 8) * 8);
    *reinterpret_cast<ushort8v*>(dst) = pk;
  }
  {
    const int vcol = tid >> 3;
    const int rg   = tid & 7;
    short4v pk;
    #pragma unroll
    for (int j = 0; j < 4; ++j) pk[j] = (short)f2bf(Red[(rg * 4 + j) * LP + 128 + vcol]);
    *reinterpret_cast<short4v*>(Vt + (size_t)vcol * (BATCH * SEQ) + grow0 + rg * 4) = pk;
  }
}

// ---------------- flash attention partials: 32x32 MFMA, causal, kv-split ----------------
// Block: 256 thr = 4 waves; wave wq owns 32 q-rows; block q-span = 128 (QB).
// LDS K [64key][64d], V^T [64d][64key], both XOR-swizzled (byte ^= (row&7)<<4).
template<int CHUNK>
__global__ __launch_bounds__(256, 4) void attn_partial(
    const unsigned short* __restrict__ Qb, const unsigned short* __restrict__ Kb,
    const unsigned short* __restrict__ Vt,
    unsigned short* __restrict__ Opart, float* __restrict__ Mpart, float* __restrict__ Lpart){
  constexpr int QB  = 128;
  constexpr int GS  = CHUNK / QB;
  constexpr int NG  = SEQ / CHUNK;
  constexpr int PCB = GS * NG * (NG + 1) / 2;

  __shared__ unsigned short Ks[64 * 64];
  __shared__ unsigned short Vs[64 * 64];

  const int b = blockIdx.x / PCB;
  const int g = blockIdx.x % PCB;
  int a = 0, accb = 0;
  while (g >= accb + GS * (a + 1)) { accb += GS * (a + 1); ++a; }
  const int rem = g - accb;
  const int qj  = a * GS + rem / (a + 1);          // 128-row q-block
  const int c   = rem % (a + 1);                   // key chunk

  const int tid  = threadIdx.x;
  const int lane = tid & 63;
  const int wq   = tid >> 6;                       // wave 0..3 -> q-strip
  const int l31  = lane & 31;
  const int lh   = lane >> 5;
  const bool lo  = (lane < 32);

  const size_t bbase = (size_t)b * SEQ * HS;
  const int qb0    = qj * QB + wq * 32;
  const int gq     = qb0 + l31;
  const int cstart = c * CHUNK;
  const int kend   = min(cstart + CHUNK, qj * QB + QB);
  const int ntile  = (kend - cstart) >> 6;

  // Q fragments (B operand): lane holds Q[qb0+l31][ds*16 + 8*lh + 0..7]
  short8v qf[4];
  #pragma unroll
  for (int ds = 0; ds < 4; ++ds)
    qf[ds] = *reinterpret_cast<const short8v*>(Qb + bbase + (size_t)(qb0 + l31) * HS + ds * 16 + 8 * lh);

  float m = -1e30f, lsum = 0.f;
  float16v o0 = {0,0,0,0,0,0,0,0,0,0,0,0,0,0,0,0};
  float16v o1 = {0,0,0,0,0,0,0,0,0,0,0,0,0,0,0,0};

  // staging: thread loads 32B of K row srow + 32B of V^T row srow
  const int srow = tid >> 2;                       // 0..63
  const int sseg = tid & 3;                        // 16-ushort segment
  const unsigned short* Kg = Kb + bbase + (size_t)(cstart + srow) * HS + sseg * 16;
  const unsigned short* Vg = Vt + (size_t)srow * (BATCH * SEQ) + b * SEQ + cstart + sseg * 16;
  ushort8v kr0, kr1, vr0, vr1;
  kr0 = reinterpret_cast<const ushort8v*>(Kg)[0];
  kr1 = reinterpret_cast<const ushort8v*>(Kg)[1];
  vr0 = reinterpret_cast<const ushort8v*>(Vg)[0];
  vr1 = reinterpret_cast<const ushort8v*>(Vg)[1];
  const int wb   = srow * 128 + sseg * 32;
  const int swz  = (srow & 7) << 4;
  char* KsB = reinterpret_cast<char*>(Ks);
  char* VsB = reinterpret_cast<char*>(Vs);

  for (int t = 0; t < ntile; ++t){
    *reinterpret_cast<ushort8v*>(KsB + ((wb     ) ^ swz)) = kr0;
    *reinterpret_cast<ushort8v*>(KsB + ((wb + 16) ^ swz)) = kr1;
    *reinterpret_cast<ushort8v*>(VsB + ((wb     ) ^ swz)) = vr0;
    *reinterpret_cast<ushort8v*>(VsB + ((wb + 16) ^ swz)) = vr1;
    __syncthreads();
    if (t + 1 < ntile){
      const unsigned short* Kn = Kg + (size_t)(t + 1) * 64 * HS;
      const unsigned short* Vn = Vg + (t + 1) * 64;
      kr0 = reinterpret_cast<const ushort8v*>(Kn)[0];
      kr1 = reinterpret_cast<const ushort8v*>(Kn)[1];
      vr0 = reinterpret_cast<const ushort8v*>(Vn)[0];
      vr1 = reinterpret_cast<const ushort8v*>(Vn)[1];
    }

    const int k0 = cstart + t * 64;
    if (k0 <= qb0 + 31){
      // ---- S^T = K * Q^T, two 32-key tiles ----
      const float16v z16 = {0,0,0,0,0,0,0,0,0,0,0,0,0,0,0,0};
      float16v st0 = z16, st1;
      #pragma unroll
      for (int ds = 0; ds < 4; ++ds){
        const int byte0 = ((l31 * 128 + ds * 32 + lh * 16) ^ ((l31 & 7) << 4));
        st0 = mfma32(*reinterpret_cast<const short8v*>(KsB + byte0), qf[ds], st0);
      }
      const bool do1 = (k0 + 32 <= qb0 + 31);
      if (do1){
        st1 = z16;
        #pragma unroll
        for (int ds = 0; ds < 4; ++ds){
          const int byte1 = (((32 + l31) * 128 + ds * 32 + lh * 16) ^ ((l31 & 7) << 4));
          st1 = mfma32(*reinterpret_cast<const short8v*>(KsB + byte1), qf[ds], st1);
        }
      } else {
        #pragma unroll
        for (int r = 0; r < 16; ++r) st1[r] = -1e30f;
      }
      // ---- causal mask (only near-diagonal tiles) ----
      if (k0 + 31 > qb0){
        #pragma unroll
        for (int r = 0; r < 16; ++r){
          const int key = k0 + (r & 3) + 8 * (r >> 2) + 4 * lh;
          if (key > gq) st0[r] = -1e30f;
        }
      }
      if (do1 && (k0 + 63 > qb0)){
        #pragma unroll
        for (int r = 0; r < 16; ++r){
          const int key = k0 + 32 + (r & 3) + 8 * (r >> 2) + 4 * lh;
          if (key > gq) st1[r] = -1e30f;
        }
      }
      // ---- online softmax (lane pair L/L+32 shares q-row) ----
      float pmax = st0[0];
      #pragma unroll
      for (int r = 1; r < 16; ++r) pmax = fmaxf(pmax, st0[r]);
      #pragma unroll
      for (int r = 0; r < 16; ++r) pmax = fmaxf(pmax, st1[r]);
      pmax = fmaxf(pmax, __shfl_xor(pmax, 32, 64));
      const float mnew = fmaxf(m, pmax);
      const float corr = exp2f(m - mnew);
      m = mnew;
      float ps = 0.f;
      #pragma unroll
      for (int r = 0; r < 16; ++r){ st0[r] = exp2f(st0[r] - mnew); ps += st0[r]; }
      #pragma unroll
      for (int r = 0; r < 16; ++r){ st1[r] = exp2f(st1[r] - mnew); ps += st1[r]; }
      ps += __shfl_xor(ps, 32, 64);
      lsum = lsum * corr + ps;
      #pragma unroll
      for (int r = 0; r < 16; ++r){ o0[r] *= corr; o1[r] *= corr; }

      // ---- P^T B-frags: 4 slices of 16 keys via pack + lane^32 half-exchange ----
      short8v pf[4];
      #define MAKE_PF(ST, BASE, OUT) { \
        int d01 = pk2(ST[BASE+0], ST[BASE+1]); \
        int d23 = pk2(ST[BASE+2], ST[BASE+3]); \
        int d45 = pk2(ST[BASE+4], ST[BASE+5]); \
        int d67 = pk2(ST[BASE+6], ST[BASE+7]); \
        int s01 = __shfl_xor(d01, 32, 64), s23 = __shfl_xor(d23, 32, 64); \
        int s45 = __shfl_xor(d45, 32, 64), s67 = __shfl_xor(d67, 32, 64); \
        int4 wi; \
        wi.x = lo ? d01 : s45;  wi.y = lo ? d23 : s67; \
        wi.z = lo ? s01 : d45;  wi.w = lo ? s23 : d67; \
        OUT = *reinterpret_cast<short8v*>(&wi); }
      MAKE_PF(st0, 0, pf[0])
      MAKE_PF(st0, 8, pf[1])
      MAKE_PF(st1, 0, pf[2])
      MAKE_PF(st1, 8, pf[3])
      #undef MAKE_PF

      // ---- O^T += V^T * P^T ----
      #pragma unroll
      for (int s = 0; s < 4; ++s){
        const int byteA = ((l31 * 128 + s * 32 + lh * 16) ^ ((l31 & 7) << 4));
        o0 = mfma32(*reinterpret_cast<const short8v*>(VsB + byteA), pf[s], o0);
      }
      #pragma unroll
      for (int s = 0; s < 4; ++s){
        const int byteB = (((32 + l31) * 128 + s * 32 + lh * 16) ^ ((l31 & 7) << 4));
        o1 = mfma32(*reinterpret_cast<const short8v*>(VsB + byteB), pf[s], o1);
      }
    }
    __syncthreads();
  }

  // ---- write partial (bf16 O, fp32 m/l) ----
  const int prow = (b * PCB + g) * QB + wq * 32 + l31;
  unsigned short* Od = Opart + (size_t)prow * 64;
  #define WRITE_O(OO, DT) { \
    _Pragma("unroll") \
    for (int quad = 0; quad < 4; ++quad){ \
      short4v pkk; \
      _Pragma("unroll") \
      for (int r = 0; r < 4; ++r) pkk[r] = (short)f2bf(OO[quad * 4 + r]); \
      *reinterpret_cast<short4v*>(Od + DT * 32 + 8 * quad + 4 * lh) = pkk; } }
  WRITE_O(o0, 0)
  WRITE_O(o1, 1)
  #undef WRITE_O
  if (lo){
    Mpart[prow] = m;
    Lpart[prow] = lsum;
  }
}

// ---------------- combine partials ----------------
template<int CHUNK>
__global__ __launch_bounds__(256) void combine_kernel(
    const unsigned short* __restrict__ Opart, const float* __restrict__ Mpart,
    const float* __restrict__ Lpart, float* __restrict__ out){
  constexpr int QB  = 128;
  constexpr int GS  = CHUNK / QB;
  constexpr int NG  = SEQ / CHUNK;
  constexpr int PCB = GS * NG * (NG + 1) / 2;
  const int gid = blockIdx.x * 4 + (threadIdx.x >> 6);   // global row 0..16383
  const int d   = threadIdx.x & 63;
  const int b   = gid >> 12;
  const int q   = gid & (SEQ - 1);
  const int qj  = q >> 7;                                // 128-row q-block
  const int A   = qj / GS;
  const int nch = A + 1;
  const int p0  = b * PCB + GS * A * (A + 1) / 2 + (qj - A * GS) * (A + 1);
  const int ql  = q & (QB - 1);

  float M = -1e30f;
  for (int cc = 0; cc < nch; ++cc) M = fmaxf(M, Mpart[(p0 + cc) * QB + ql]);
  float L = 0.f, O = 0.f;
  for (int cc = 0; cc < nch; ++cc){
    const float s = exp2f(Mpart[(p0 + cc) * QB + ql] - M);
    L += s * Lpart[(p0 + cc) * QB + ql];
    const unsigned short ob = Opart[((size_t)(p0 + cc) * QB + ql) * 64 + d];
    O += s * __uint_as_float((unsigned)ob << 16);
  }
  out[(size_t)gid * 64 + d] = O / L;
}

extern "C" void kernel_launch(void* const* d_in, const int* in_sizes, int n_in,
                              void* d_out, int out_size, void* d_ws, size_t ws_size,
                              hipStream_t stream){
  const float* x  = (const float*)d_in[0];
  const float* Wq = (const float*)d_in[1];
  const float* Wk = (const float*)d_in[2];
  const float* Wv = (const float*)d_in[3];

  const size_t nqkv = (size_t)BATCH * SEQ * HS;
  unsigned short* Qb = (unsigned short*)d_ws;
  unsigned short* Kb = Qb + nqkv;
  unsigned short* Vt = Kb + nqkv;                     // [HS][BATCH*SEQ]
  unsigned short* Wpack = Vt + nqkv;                  // 196608 ushorts = 384 KB
  unsigned short* Opart = Wpack + (size_t)196608;

  pack32_kernel<<<96, 256, 0, stream>>>(Wq, Wk, Wv, Wpack);
  proj_mfma<<<(BATCH * SEQ) / 32, 512, 0, stream>>>(x, Wpack, Qb, Kb, Vt);

  constexpr int PCB256  = 2 * 16 * 17 / 2;    // 272
  constexpr int PCB1024 = 8 * 4 * 5 / 2;      // 80
  constexpr int PCB4096 = 32 * 1 * 2 / 2;     // 32
  const size_t base_bytes = (3 * nqkv + (size_t)196608) * sizeof(unsigned short);
  auto pbytes = [](int pcb){ return (size_t)BATCH * pcb * 128 * (64 * 2 + 8); };

  if (ws_size >= base_bytes + pbytes(PCB256)){
    float* Mpart = (float*)(Opart + (size_t)BATCH * PCB256 * 128 * 64);
    float* Lpart = Mpart + (size_t)BATCH * PCB256 * 128;
    attn_partial<256><<<BATCH * PCB256, 256, 0, stream>>>(Qb, Kb, Vt, Opart, Mpart, Lpart);
    combine_kernel<256><<<BATCH * SEQ / 4, 256, 0, stream>>>(Opart, Mpart, Lpart, (float*)d_out);
  } else if (ws_size >= base_bytes + pbytes(PCB1024)){
    float* Mpart = (float*)(Opart + (size_t)BATCH * PCB1024 * 128 * 64);
    float* Lpart = Mpart + (size_t)BATCH * PCB1024 * 128;
    attn_partial<1024><<<BATCH * PCB1024, 256, 0, stream>>>(Qb, Kb, Vt, Opart, Mpart, Lpart);
    combine_kernel<1024><<<BATCH * SEQ / 4, 256, 0, stream>>>(Opart, Mpart, Lpart, (float*)d_out);
  } else {
    float* Mpart = (float*)(Opart + (size_t)BATCH * PCB4096 * 128 * 64);
    float* Lpart = Mpart + (size_t)BATCH * PCB4096 * 128;
    attn_partial<4096><<<BATCH * PCB4096, 256, 0, stream>>>(Qb, Kb, Vt, Opart, Mpart, Lpart);
    combine_kernel<4096><<<BATCH * SEQ / 4, 256, 0, stream>>>(Opart, Mpart, Lpart, (float*)d_out);
  }
}